// Round 20
// baseline (113.241 us; speedup 1.0000x reference)
//
#include <hip/hip_runtime.h>
#include <stdint.h>

// ---------- types ----------
typedef __attribute__((ext_vector_type(8))) short bf16x8;
typedef __attribute__((ext_vector_type(4))) float f32x4;

// ---------- helpers ----------
__device__ __forceinline__ unsigned short f2bf(float f) {
  union { float f; unsigned int u; } un; un.f = f;
  unsigned int r = un.u + 0x7fffu + ((un.u >> 16) & 1u);
  return (unsigned short)(r >> 16);
}

__device__ __forceinline__ float tanh_fast(float x) {
  x = fminf(15.f, fmaxf(-15.f, x));
  float e = __expf(2.f * x);
  return (e - 1.f) / (e + 1.f);
}

__device__ __forceinline__ unsigned int cvt_pk_bf16(float lo, float hi) {
  unsigned int r;
  asm("v_cvt_pk_bf16_f32 %0, %1, %2" : "=v"(r) : "v"(lo), "v"(hi));
  return r;
}

// async global->LDS, 16B per lane. lds dest must be wave-uniform base.
__device__ __forceinline__ void gload_lds16(const void* g, void* l) {
  __builtin_amdgcn_global_load_lds(
      (const __attribute__((address_space(1))) unsigned int*)(unsigned long long)g,
      (__attribute__((address_space(3))) unsigned int*)(unsigned int)(unsigned long long)l,
      16, 0, 0);
}

// ---------- merged weight transpose/convert + p0 (null-token path) ----------
__global__ __launch_bounds__(256) void cvt_weights_p0(
    const float* __restrict__ Wt_in, const float* __restrict__ Wj_in,
    const float* __restrict__ ynull, const float* __restrict__ b_trans,
    const float* __restrict__ W_p0, const float* __restrict__ b_p0,
    unsigned short* __restrict__ wt, unsigned short* __restrict__ wj,
    float* __restrict__ p0buf) {
  if (blockIdx.x < 1536) {
    const int i = blockIdx.x * 256 + threadIdx.x;
    if (i < 512 * 512) {
      const int c = i >> 9, r = i & 511;
      wt[i] = f2bf(Wt_in[(size_t)r * 512 + c]);
    } else {
      const int j = i - 512 * 512;  // < 512*256
      const int c = j >> 9, r = j & 511;
      wj[j] = f2bf(Wj_in[(size_t)r * 257 + c]);
    }
    return;
  }
  // ---- p0 block (256 threads, each covers hh and hh+256) ----
  __shared__ float red[256];
  const int hh = threadIdx.x;
  float a0 = 0.f, a1 = 0.f;
  for (int e = 0; e < 512; ++e) {
    const float y = ynull[e];
    a0 = fmaf(y, Wt_in[(size_t)e * 512 + hh], a0);
    a1 = fmaf(y, Wt_in[(size_t)e * 512 + hh + 256], a1);
  }
  red[hh] = tanhf(a0 + b_trans[hh]) * W_p0[hh] +
            tanhf(a1 + b_trans[hh + 256]) * W_p0[hh + 256];
  __syncthreads();
  for (int s = 128; s > 0; s >>= 1) {
    if (hh < s) red[hh] += red[hh + s];
    __syncthreads();
  }
  if (hh == 0) {
    const float z = red[0] + b_p0[0];
    const float p0 = 1.f / (1.f + __expf(-z));
    p0buf[0] = p0;
    p0buf[1] = 1.f - p0;
  }
}

// LDS slot swizzle: 16B slot s of 64B row r holds data slot s ^ ((r>>1)&3).

// ---------- GEMM1: C = tanh(Af32 @ Bt^T + bias) -> bf16 ----------
// R9 128x128 body verbatim; ONLY change: __launch_bounds__(256,4) + grid
// (256,4) -> 4 blocks/CU resident (was 2). Other blocks' compute hides each
// block's stage-drain stall (m114 inter-block overlap).
__global__ __launch_bounds__(256, 4) void gemm_af32(
    const float* __restrict__ A, const unsigned short* __restrict__ Bt,
    const float* __restrict__ bias, unsigned short* __restrict__ Cout,
    int M, int N, int K) {
  __shared__ unsigned short sA[128 * 32];
  __shared__ unsigned short sB[128 * 32];
  const int tid = threadIdx.x;
  const int lane = tid & 63;
  const int wave = tid >> 6;
  const int wr = wave >> 1, wc = wave & 1;
  const int m0 = blockIdx.x * 128, n0 = blockIdx.y * 128;

  f32x4 acc[4][4] = {};

  const int srow = lane >> 2;            // 0..15
  const int sl = lane & 3;               // slot 0..3
  const int scol = sl * 8;               // linear elem col (A global load)
  const int wsz = (srow >> 1) & 3;       // row-swizzle key
  const int scolw = (sl ^ wsz) * 8;      // swizzled slot (LDS write / B source)
  const int c0 = wave * 2, c1 = wave * 2 + 1;
  const float* Af0 = A + (size_t)(m0 + c0 * 16 + srow) * K + scol;
  const float* Af1 = A + (size_t)(m0 + c1 * 16 + srow) * K + scol;
  const unsigned short* Br0 = Bt + (size_t)(n0 + c0 * 16 + srow) * K + scolw;
  const unsigned short* Br1 = Bt + (size_t)(n0 + c1 * 16 + srow) * K + scolw;

  // prologue: load A regs for kk=0
  float4 a00 = *reinterpret_cast<const float4*>(Af0);
  float4 a01 = *reinterpret_cast<const float4*>(Af0 + 4);
  float4 a10 = *reinterpret_cast<const float4*>(Af1);
  float4 a11 = *reinterpret_cast<const float4*>(Af1 + 4);

  const int r15 = lane & 15;
  const int oslot = ((lane >> 4) ^ ((r15 >> 1) & 3)) * 8;

  for (int kk = 0; kk < K; kk += 32) {
    __syncthreads();
    // B gloads first (latency overlaps A pack), then A pack -> LDS
    gload_lds16(Br0 + kk, &sB[c0 * 512]);
    gload_lds16(Br1 + kk, &sB[c1 * 512]);
    {
      union { unsigned int u[4]; bf16x8 v; } p;
      p.u[0] = cvt_pk_bf16(a00.x, a00.y);
      p.u[1] = cvt_pk_bf16(a00.z, a00.w);
      p.u[2] = cvt_pk_bf16(a01.x, a01.y);
      p.u[3] = cvt_pk_bf16(a01.z, a01.w);
      *reinterpret_cast<bf16x8*>(&sA[c0 * 512 + srow * 32 + scolw]) = p.v;
      p.u[0] = cvt_pk_bf16(a10.x, a10.y);
      p.u[1] = cvt_pk_bf16(a10.z, a10.w);
      p.u[2] = cvt_pk_bf16(a11.x, a11.y);
      p.u[3] = cvt_pk_bf16(a11.z, a11.w);
      *reinterpret_cast<bf16x8*>(&sA[c1 * 512 + srow * 32 + scolw]) = p.v;
    }
    __syncthreads();
    // prefetch next A tile (hides under compute)
    if (kk + 32 < K) {
      a00 = *reinterpret_cast<const float4*>(Af0 + kk + 32);
      a01 = *reinterpret_cast<const float4*>(Af0 + kk + 36);
      a10 = *reinterpret_cast<const float4*>(Af1 + kk + 32);
      a11 = *reinterpret_cast<const float4*>(Af1 + kk + 36);
    }
    bf16x8 af[4], bfr[4];
#pragma unroll
    for (int mi = 0; mi < 4; ++mi)
      af[mi] = *reinterpret_cast<const bf16x8*>(
          &sA[(wr * 64 + mi * 16 + r15) * 32 + oslot]);
#pragma unroll
    for (int ni = 0; ni < 4; ++ni)
      bfr[ni] = *reinterpret_cast<const bf16x8*>(
          &sB[(wc * 64 + ni * 16 + r15) * 32 + oslot]);
#pragma unroll
    for (int mi = 0; mi < 4; ++mi)
#pragma unroll
      for (int ni = 0; ni < 4; ++ni)
        acc[mi][ni] = __builtin_amdgcn_mfma_f32_16x16x32_bf16(
            af[mi], bfr[ni], acc[mi][ni], 0, 0, 0);
  }

  const int crow0 = m0 + wr * 64 + (lane >> 4) * 4;
  const int ccol0 = n0 + wc * 64 + r15;
#pragma unroll
  for (int mi = 0; mi < 4; ++mi) {
#pragma unroll
    for (int ni = 0; ni < 4; ++ni) {
      const int gcol = ccol0 + ni * 16;
      const float bv = bias[gcol];
#pragma unroll
      for (int r = 0; r < 4; ++r) {
        const int grow = crow0 + mi * 16 + r;
        Cout[(size_t)grow * N + gcol] = f2bf(tanh_fast(acc[mi][ni][r] + bv));
      }
    }
  }
}

// ---------- fused GEMM2 + windowed softmax -> jw bf16 ----------
// Block: 64 rows x N=256 (full row -> softmax window is block-local).
#define LG_STRIDE 260
__global__ __launch_bounds__(256, 2) void gemm2_sm(
    const unsigned short* __restrict__ A,    // ts16 [32768][512]
    const unsigned short* __restrict__ Bt,   // wj16t [256][512]
    const float* __restrict__ bias,          // b_jump (cols 0..255)
    const float* __restrict__ p0buf,
    unsigned short* __restrict__ jwout) {    // [32768][128]
  __shared__ __align__(16) char smem[64 * LG_STRIDE * 4];  // 66560B; stage uses 2x20480
  const int tid = threadIdx.x;
  const int lane = tid & 63;
  const int wave = tid >> 6;
  const int m0 = blockIdx.x * 64;
  const int r15 = lane & 15;
  const int q = lane >> 4;
  const int wr = wave >> 1, wc = wave & 1;

  f32x4 acc[2][8] = {};

  const int srow = lane >> 2;
  const int sl = lane & 3;
  const int scolw = ((sl ^ ((srow >> 1) & 3))) * 8;
  const int oslot = ((q ^ ((r15 >> 1) & 3))) * 8;

  auto stage = [&](int bi, int t) {
    unsigned short* base = (unsigned short*)(smem + bi * 20480);
#pragma unroll
    for (int cc = 0; cc < 5; ++cc) {
      const int chunk = wave + cc * 4;  // 0..19
      if (chunk < 4) {
        gload_lds16(A + (size_t)(m0 + chunk * 16 + srow) * 512 + t * 32 + scolw,
                    base + chunk * 512);
      } else {
        gload_lds16(Bt + (size_t)((chunk - 4) * 16 + srow) * 512 + t * 32 + scolw,
                    base + 2048 + (chunk - 4) * 512);
      }
    }
  };
  auto compute = [&](int bi) {
    const unsigned short* base = (const unsigned short*)(smem + bi * 20480);
    bf16x8 af[2], bfr[8];
#pragma unroll
    for (int mi = 0; mi < 2; ++mi)
      af[mi] = *reinterpret_cast<const bf16x8*>(
          &base[(wr * 32 + mi * 16 + r15) * 32 + oslot]);
#pragma unroll
    for (int ni = 0; ni < 8; ++ni)
      bfr[ni] = *reinterpret_cast<const bf16x8*>(
          &base[2048 + (wc * 128 + ni * 16 + r15) * 32 + oslot]);
#pragma unroll
    for (int mi = 0; mi < 2; ++mi)
#pragma unroll
      for (int ni = 0; ni < 8; ++ni)
        acc[mi][ni] = __builtin_amdgcn_mfma_f32_16x16x32_bf16(
            af[mi], bfr[ni], acc[mi][ni], 0, 0, 0);
  };

  stage(0, 0);
  __syncthreads();
  for (int t = 0; t < 16; ++t) {
    if (t + 1 < 16) stage((t + 1) & 1, t + 1);
    compute(t & 1);
    __syncthreads();
  }

  // park logits (+bias) in LDS f32 [64][LG_STRIDE]
  float* lg = (float*)smem;
#pragma unroll
  for (int mi = 0; mi < 2; ++mi) {
#pragma unroll
    for (int ni = 0; ni < 8; ++ni) {
      const int col = wc * 128 + ni * 16 + r15;
      const float bv = bias[col];
#pragma unroll
      for (int r = 0; r < 4; ++r) {
        const int rowL = wr * 32 + mi * 16 + q * 4 + r;
        lg[rowL * LG_STRIDE + col] = acc[mi][ni][r] + bv;
      }
    }
  }
  __syncthreads();

  // windowed softmax: thread (rowL = tid>>2, p = tid&3) covers k = p*32..p*32+31
  const int rowL = tid >> 2, p = tid & 3;
  const int grow = m0 + rowL;
  const int i = grow & 127;
  float* lrow = lg + rowL * LG_STRIDE + (128 - i) + p * 32;
  float mx = -1e30f;
#pragma unroll
  for (int j = 0; j < 32; ++j) mx = fmaxf(mx, lrow[j]);
  mx = fmaxf(mx, __shfl_xor(mx, 1));
  mx = fmaxf(mx, __shfl_xor(mx, 2));
  float s = 0.f;
#pragma unroll
  for (int j = 0; j < 32; ++j) {
    const float e = __expf(lrow[j] - mx);
    lrow[j] = e;           // own slot; no cross-thread hazard
    s += e;
  }
  s += __shfl_xor(s, 1);
  s += __shfl_xor(s, 2);
  const float scale = p0buf[1] / s;  // (1-p0)/sum
  unsigned int* orow = (unsigned int*)(jwout + (size_t)grow * 128 + p * 32);
#pragma unroll
  for (int j = 0; j < 16; ++j)
    orow[j] = cvt_pk_bf16(lrow[2 * j] * scale, lrow[2 * j + 1] * scale);
}

// ---------- fused HMM forward: in-LDS emission transpose + MFMA recursion ----
#define SE_STRIDE 264  // floats; 1056B row pitch (16B aligned), breaks pow2 banks
__global__ __launch_bounds__(256, 1) void forward_fused(
    const unsigned short* __restrict__ jwb,   // [B][128][128] bf16
    const float* __restrict__ emission,       // [B][256][64]
    const float* __restrict__ p0buf, const int* __restrict__ slen_p,
    const int* __restrict__ tlen_p, float* __restrict__ out) {
  __shared__ __align__(16) float se[64 * SE_STRIDE];
  __shared__ __align__(16) unsigned short gl16[128];
  const int b = blockIdx.x;
  const int tid = threadIdx.x;
  const float* eb = emission + (size_t)b * 16384;

  bf16x8 bfr[4][8];
  const int l = tid & 63;
  const int m = l & 15;
  const int q = l >> 4;

  if (tid >= 64) {
    // transpose emission[b] ([256][64] -> se[t][half*128+m*8+nt])
#pragma unroll
    for (int it = 0; it < 6; ++it) {
      const int tau = (tid - 64) + 192 * it;
      if (tau < 1024) {
        const int t0 = (tau & 15) * 4;
        const int mm = (tau >> 4) & 15;
        const int nt0 = ((tau >> 8) & 1) * 4;
        const int half = (tau >> 9) & 1;
        const int kbase = half * 128 + nt0 * 16 + mm;
        const float4 v0 = *reinterpret_cast<const float4*>(&eb[(size_t)(kbase) * 64 + t0]);
        const float4 v1 = *reinterpret_cast<const float4*>(&eb[(size_t)(kbase + 16) * 64 + t0]);
        const float4 v2 = *reinterpret_cast<const float4*>(&eb[(size_t)(kbase + 32) * 64 + t0]);
        const float4 v3 = *reinterpret_cast<const float4*>(&eb[(size_t)(kbase + 48) * 64 + t0]);
        const int jinv0 = half * 128 + mm * 8 + nt0;
        float* d = &se[(size_t)t0 * SE_STRIDE + jinv0];
        *reinterpret_cast<float4*>(d) = (float4){v0.x, v1.x, v2.x, v3.x};
        *reinterpret_cast<float4*>(d + SE_STRIDE) = (float4){v0.y, v1.y, v2.y, v3.y};
        *reinterpret_cast<float4*>(d + 2 * SE_STRIDE) = (float4){v0.z, v1.z, v2.z, v3.z};
        *reinterpret_cast<float4*>(d + 3 * SE_STRIDE) = (float4){v0.w, v1.w, v2.w, v3.w};
      }
    }
  } else {
    // wave 0: build jw B-frags: bfr[kt][nt][j] = jw[kt*32+q*8+j][nt*16+m]
    const unsigned short* jwt = jwb + (size_t)b * 16384;
#pragma unroll
    for (int kt = 0; kt < 4; ++kt) {
      const int r0 = kt * 32 + q * 8;
#pragma unroll
      for (int nt = 0; nt < 8; ++nt) {
        const int c = nt * 16 + m;
        bf16x8 v;
#pragma unroll
        for (int j = 0; j < 8; ++j) v[j] = (short)jwt[(size_t)(r0 + j) * 128 + c];
        bfr[kt][nt] = v;
      }
    }
  }
  __syncthreads();
  if (tid >= 64) return;

  const float p0 = p0buf[0];
  const int S = slen_p[b];
  const int T = tlen_p[b];

  float gown[8];
  {
    const float4 i0a = *reinterpret_cast<const float4*>(&se[m * 8]);
    const float4 i0b = *reinterpret_cast<const float4*>(&se[m * 8 + 4]);
    const float4 i1a = *reinterpret_cast<const float4*>(&se[128 + m * 8]);
    const float4 i1b = *reinterpret_cast<const float4*>(&se[128 + m * 8 + 4]);
    gown[0] = i0a.x + i1a.x; gown[1] = i0a.y + i1a.y;
    gown[2] = i0a.z + i1a.z; gown[3] = i0a.w + i1a.w;
    gown[4] = i0b.x + i1b.x; gown[5] = i0b.y + i1b.y;
    gown[6] = i0b.z + i1b.z; gown[7] = i0b.w + i1b.w;
  }
  gl16[(2 * q) * 16 + m]     = f2bf(gown[2 * q]);
  gl16[(2 * q + 1) * 16 + m] = f2bf(gown[2 * q + 1]);

  for (int t = 1; t < S; ++t) {
    const float* st = &se[(size_t)t * SE_STRIDE];
    const float4 pe0a = *reinterpret_cast<const float4*>(&st[m * 8]);
    const float4 pe0b = *reinterpret_cast<const float4*>(&st[m * 8 + 4]);
    const float4 pe1a = *reinterpret_cast<const float4*>(&st[128 + m * 8]);
    const float4 pe1b = *reinterpret_cast<const float4*>(&st[128 + m * 8 + 4]);
    const float e0[8] = {pe0a.x, pe0a.y, pe0a.z, pe0a.w, pe0b.x, pe0b.y, pe0b.z, pe0b.w};
    const float e1[8] = {pe1a.x, pe1a.y, pe1a.z, pe1a.w, pe1b.x, pe1b.y, pe1b.z, pe1b.w};
    float h[8];
#pragma unroll
    for (int nt = 0; nt < 8; ++nt) h[nt] = gown[nt] * (p0 * e1[nt]);
    bf16x8 af[4];
#pragma unroll
    for (int kt = 0; kt < 4; ++kt)
      af[kt] = *reinterpret_cast<const bf16x8*>(&gl16[kt * 32 + q * 8]);
    f32x4 acc[8];
#pragma unroll
    for (int nt = 0; nt < 8; ++nt) {
      f32x4 a = __builtin_amdgcn_mfma_f32_16x16x32_bf16(
          af[0], bfr[0][nt], (f32x4){0.f, 0.f, 0.f, 0.f}, 0, 0, 0);
      a = __builtin_amdgcn_mfma_f32_16x16x32_bf16(af[1], bfr[1][nt], a, 0, 0, 0);
      a = __builtin_amdgcn_mfma_f32_16x16x32_bf16(af[2], bfr[2][nt], a, 0, 0, 0);
      acc[nt] = __builtin_amdgcn_mfma_f32_16x16x32_bf16(af[3], bfr[3][nt], a, 0, 0, 0);
    }
#pragma unroll
    for (int nt = 0; nt < 8; ++nt) gown[nt] = fmaf(acc[nt][0], e0[nt], h[nt]);
    gl16[(2 * q) * 16 + m]     = f2bf(gown[2 * q]);
    gl16[(2 * q + 1) * 16 + m] = f2bf(gown[2 * q + 1]);
  }

  float val = 0.f;
#pragma unroll
  for (int nt = 0; nt < 8; ++nt)
    if (nt * 16 + m < T) val += gown[nt];
#pragma unroll
  for (int off = 1; off < 16; off <<= 1) val += __shfl_xor(val, off);
  if (l == 0) out[b] = logf(val + 1e-29f);
}

// ---------- launch ----------
extern "C" void kernel_launch(void* const* d_in, const int* in_sizes, int n_in,
                              void* d_out, int out_size, void* d_ws, size_t ws_size,
                              hipStream_t stream) {
  const float* y_hidden = (const float*)d_in[0];   // [256,128,512]
  const float* y_null   = (const float*)d_in[1];   // [1,1,512]
  const float* W_trans  = (const float*)d_in[2];   // [512,512]
  const float* b_trans  = (const float*)d_in[3];   // [512]
  const float* W_jump   = (const float*)d_in[4];   // [512,257]
  const float* b_jump   = (const float*)d_in[5];   // [257]
  const float* W_p0     = (const float*)d_in[6];   // [512,1]
  const float* b_p0     = (const float*)d_in[7];   // [1]
  const float* emission = (const float*)d_in[8];   // [256,256,64]
  const int* slen = (const int*)d_in[9];
  const int* tlen = (const int*)d_in[10];
  float* out = (float*)d_out;

  char* ws = (char*)d_ws;
  unsigned short* ts16  = (unsigned short*)ws;               // 33,554,432 B
  unsigned short* wt16t = (unsigned short*)(ws + 50331648);  // 524,288 B
  unsigned short* wj16t = (unsigned short*)(ws + 50855936);  // 262,144 B
  float* p0buf          = (float*)(ws + 51118080);           // 256 B
  unsigned short* jwb16 = (unsigned short*)(ws + 51118336);  // 8,388,608 B

  cvt_weights_p0<<<dim3(1537), dim3(256), 0, stream>>>(
      W_trans, W_jump, y_null, b_trans, W_p0, b_p0, wt16t, wj16t, p0buf);

  // GEMM1: ts = tanh(y_f32 @ W_trans + b) -> bf16 (128x128, 4 blocks/CU)
  gemm_af32<<<dim3(256, 4), dim3(256), 0, stream>>>(y_hidden, wt16t, b_trans, ts16,
                                                    32768, 512, 512);
  // GEMM2 + windowed softmax fused -> jw bf16 (logits never touch HBM)
  gemm2_sm<<<dim3(512), dim3(256), 0, stream>>>(ts16, wj16t, b_jump, p0buf, jwb16);
  // fused emission-transpose + HMM forward + masked log-sum
  forward_fused<<<dim3(256), dim3(256), 0, stream>>>(jwb16, emission, p0buf,
                                                     slen, tlen, out);
}

// Round 21
// 109.094 us; speedup vs baseline: 1.0380x; 1.0380x over previous
//
#include <hip/hip_runtime.h>
#include <stdint.h>

// ---------- types ----------
typedef __attribute__((ext_vector_type(8))) short bf16x8;
typedef __attribute__((ext_vector_type(4))) float f32x4;

// ---------- helpers ----------
__device__ __forceinline__ unsigned short f2bf(float f) {
  union { float f; unsigned int u; } un; un.f = f;
  unsigned int r = un.u + 0x7fffu + ((un.u >> 16) & 1u);
  return (unsigned short)(r >> 16);
}

__device__ __forceinline__ float tanh_fast(float x) {
  x = fminf(15.f, fmaxf(-15.f, x));
  float e = __expf(2.f * x);
  return (e - 1.f) / (e + 1.f);
}

__device__ __forceinline__ unsigned int cvt_pk_bf16(float lo, float hi) {
  unsigned int r;
  asm("v_cvt_pk_bf16_f32 %0, %1, %2" : "=v"(r) : "v"(lo), "v"(hi));
  return r;
}

// async global->LDS, 16B per lane. lds dest must be wave-uniform base.
__device__ __forceinline__ void gload_lds16(const void* g, void* l) {
  __builtin_amdgcn_global_load_lds(
      (const __attribute__((address_space(1))) unsigned int*)(unsigned long long)g,
      (__attribute__((address_space(3))) unsigned int*)(unsigned int)(unsigned long long)l,
      16, 0, 0);
}

// ---------- merged weight transpose/convert + p0 (null-token path) ----------
__global__ __launch_bounds__(256) void cvt_weights_p0(
    const float* __restrict__ Wt_in, const float* __restrict__ Wj_in,
    const float* __restrict__ ynull, const float* __restrict__ b_trans,
    const float* __restrict__ W_p0, const float* __restrict__ b_p0,
    unsigned short* __restrict__ wt, unsigned short* __restrict__ wj,
    float* __restrict__ p0buf) {
  if (blockIdx.x < 1536) {
    const int i = blockIdx.x * 256 + threadIdx.x;
    if (i < 512 * 512) {
      const int c = i >> 9, r = i & 511;
      wt[i] = f2bf(Wt_in[(size_t)r * 512 + c]);
    } else {
      const int j = i - 512 * 512;  // < 512*256
      const int c = j >> 9, r = j & 511;
      wj[j] = f2bf(Wj_in[(size_t)r * 257 + c]);
    }
    return;
  }
  // ---- p0 block (256 threads, each covers hh and hh+256) ----
  __shared__ float red[256];
  const int hh = threadIdx.x;
  float a0 = 0.f, a1 = 0.f;
  for (int e = 0; e < 512; ++e) {
    const float y = ynull[e];
    a0 = fmaf(y, Wt_in[(size_t)e * 512 + hh], a0);
    a1 = fmaf(y, Wt_in[(size_t)e * 512 + hh + 256], a1);
  }
  red[hh] = tanhf(a0 + b_trans[hh]) * W_p0[hh] +
            tanhf(a1 + b_trans[hh + 256]) * W_p0[hh + 256];
  __syncthreads();
  for (int s = 128; s > 0; s >>= 1) {
    if (hh < s) red[hh] += red[hh + s];
    __syncthreads();
  }
  if (hh == 0) {
    const float z = red[0] + b_p0[0];
    const float p0 = 1.f / (1.f + __expf(-z));
    p0buf[0] = p0;
    p0buf[1] = 1.f - p0;
  }
}

// LDS slot swizzle: 16B slot s of 64B row r holds data slot s ^ ((r>>1)&3).

// ---------- GEMM1: C = tanh(Af32 @ Bt^T + bias) -> bf16 ----------
// best-measured structure (R17, 109.6us total): 128x256 tile, 2-barrier loop,
// B gload issued first after barrier1 so its latency overlaps the A pack.
__global__ __launch_bounds__(256, 2) void gemm_af32(
    const float* __restrict__ A, const unsigned short* __restrict__ Bt,
    const float* __restrict__ bias, unsigned short* __restrict__ Cout,
    int M, int N, int K) {
  __shared__ unsigned short sA[128 * 32];        // 8KB
  __shared__ unsigned short sB[256 * 32];        // 16KB
  const int tid = threadIdx.x;
  const int lane = tid & 63;
  const int wave = tid >> 6;
  const int wr = wave >> 1, wc = wave & 1;       // wave: 64 rows x 128 cols
  const int m0 = blockIdx.x * 128, n0 = blockIdx.y * 256;

  f32x4 acc[4][8] = {};

  const int srow = lane >> 2;            // 0..15
  const int sl = lane & 3;               // slot 0..3
  const int scol = sl * 8;               // linear elem col (A global load)
  const int wsz = (srow >> 1) & 3;       // row-swizzle key
  const int scolw = (sl ^ wsz) * 8;      // swizzled slot (LDS write / B source)
  const int c0 = wave * 2, c1 = wave * 2 + 1;    // A chunks (8 x 16 rows)
  const float* Af0 = A + (size_t)(m0 + c0 * 16 + srow) * K + scol;
  const float* Af1 = A + (size_t)(m0 + c1 * 16 + srow) * K + scol;

  // prologue: load A regs for kk=0
  float4 a00 = *reinterpret_cast<const float4*>(Af0);
  float4 a01 = *reinterpret_cast<const float4*>(Af0 + 4);
  float4 a10 = *reinterpret_cast<const float4*>(Af1);
  float4 a11 = *reinterpret_cast<const float4*>(Af1 + 4);

  const int r15 = lane & 15;
  const int oslot = ((lane >> 4) ^ ((r15 >> 1) & 3)) * 8;

  for (int kk = 0; kk < K; kk += 32) {
    __syncthreads();
    // B first: 16 chunks of 16 rows; 4 per wave (pre-swizzled global source).
#pragma unroll
    for (int j = 0; j < 4; ++j) {
      const int c = wave * 4 + j;
      gload_lds16(Bt + (size_t)(n0 + c * 16 + srow) * K + kk + scolw,
                  &sB[c * 512]);
    }
    // pack current A regs -> bf16, write to LDS at swizzled slot
    {
      union { unsigned int u[4]; bf16x8 v; } p;
      p.u[0] = cvt_pk_bf16(a00.x, a00.y);
      p.u[1] = cvt_pk_bf16(a00.z, a00.w);
      p.u[2] = cvt_pk_bf16(a01.x, a01.y);
      p.u[3] = cvt_pk_bf16(a01.z, a01.w);
      *reinterpret_cast<bf16x8*>(&sA[c0 * 512 + srow * 32 + scolw]) = p.v;
      p.u[0] = cvt_pk_bf16(a10.x, a10.y);
      p.u[1] = cvt_pk_bf16(a10.z, a10.w);
      p.u[2] = cvt_pk_bf16(a11.x, a11.y);
      p.u[3] = cvt_pk_bf16(a11.z, a11.w);
      *reinterpret_cast<bf16x8*>(&sA[c1 * 512 + srow * 32 + scolw]) = p.v;
    }
    __syncthreads();
    // prefetch next A tile (hides under compute)
    if (kk + 32 < K) {
      a00 = *reinterpret_cast<const float4*>(Af0 + kk + 32);
      a01 = *reinterpret_cast<const float4*>(Af0 + kk + 36);
      a10 = *reinterpret_cast<const float4*>(Af1 + kk + 32);
      a11 = *reinterpret_cast<const float4*>(Af1 + kk + 36);
    }
    bf16x8 af[4], bfr[8];
#pragma unroll
    for (int mi = 0; mi < 4; ++mi)
      af[mi] = *reinterpret_cast<const bf16x8*>(
          &sA[(wr * 64 + mi * 16 + r15) * 32 + oslot]);
#pragma unroll
    for (int ni = 0; ni < 8; ++ni)
      bfr[ni] = *reinterpret_cast<const bf16x8*>(
          &sB[(wc * 128 + ni * 16 + r15) * 32 + oslot]);
#pragma unroll
    for (int mi = 0; mi < 4; ++mi)
#pragma unroll
      for (int ni = 0; ni < 8; ++ni)
        acc[mi][ni] = __builtin_amdgcn_mfma_f32_16x16x32_bf16(
            af[mi], bfr[ni], acc[mi][ni], 0, 0, 0);
  }

  const int crow0 = m0 + wr * 64 + (lane >> 4) * 4;
  const int ccol0 = n0 + wc * 128 + r15;
#pragma unroll
  for (int mi = 0; mi < 4; ++mi) {
#pragma unroll
    for (int ni = 0; ni < 8; ++ni) {
      const int gcol = ccol0 + ni * 16;
      const float bv = bias[gcol];
#pragma unroll
      for (int r = 0; r < 4; ++r) {
        const int grow = crow0 + mi * 16 + r;
        Cout[(size_t)grow * N + gcol] = f2bf(tanh_fast(acc[mi][ni][r] + bv));
      }
    }
  }
}

// ---------- fused GEMM2 + windowed softmax -> jw bf16 ----------
// Block: 64 rows x N=256 (full row -> softmax window is block-local).
#define LG_STRIDE 260
__global__ __launch_bounds__(256, 2) void gemm2_sm(
    const unsigned short* __restrict__ A,    // ts16 [32768][512]
    const unsigned short* __restrict__ Bt,   // wj16t [256][512]
    const float* __restrict__ bias,          // b_jump (cols 0..255)
    const float* __restrict__ p0buf,
    unsigned short* __restrict__ jwout) {    // [32768][128]
  __shared__ __align__(16) char smem[64 * LG_STRIDE * 4];  // 66560B; stage uses 2x20480
  const int tid = threadIdx.x;
  const int lane = tid & 63;
  const int wave = tid >> 6;
  const int m0 = blockIdx.x * 64;
  const int r15 = lane & 15;
  const int q = lane >> 4;
  const int wr = wave >> 1, wc = wave & 1;

  f32x4 acc[2][8] = {};

  const int srow = lane >> 2;
  const int sl = lane & 3;
  const int scolw = ((sl ^ ((srow >> 1) & 3))) * 8;
  const int oslot = ((q ^ ((r15 >> 1) & 3))) * 8;

  auto stage = [&](int bi, int t) {
    unsigned short* base = (unsigned short*)(smem + bi * 20480);
#pragma unroll
    for (int cc = 0; cc < 5; ++cc) {
      const int chunk = wave + cc * 4;  // 0..19
      if (chunk < 4) {
        gload_lds16(A + (size_t)(m0 + chunk * 16 + srow) * 512 + t * 32 + scolw,
                    base + chunk * 512);
      } else {
        gload_lds16(Bt + (size_t)((chunk - 4) * 16 + srow) * 512 + t * 32 + scolw,
                    base + 2048 + (chunk - 4) * 512);
      }
    }
  };
  auto compute = [&](int bi) {
    const unsigned short* base = (const unsigned short*)(smem + bi * 20480);
    bf16x8 af[2], bfr[8];
#pragma unroll
    for (int mi = 0; mi < 2; ++mi)
      af[mi] = *reinterpret_cast<const bf16x8*>(
          &base[(wr * 32 + mi * 16 + r15) * 32 + oslot]);
#pragma unroll
    for (int ni = 0; ni < 8; ++ni)
      bfr[ni] = *reinterpret_cast<const bf16x8*>(
          &base[2048 + (wc * 128 + ni * 16 + r15) * 32 + oslot]);
#pragma unroll
    for (int mi = 0; mi < 2; ++mi)
#pragma unroll
      for (int ni = 0; ni < 8; ++ni)
        acc[mi][ni] = __builtin_amdgcn_mfma_f32_16x16x32_bf16(
            af[mi], bfr[ni], acc[mi][ni], 0, 0, 0);
  };

  stage(0, 0);
  __syncthreads();
  for (int t = 0; t < 16; ++t) {
    if (t + 1 < 16) stage((t + 1) & 1, t + 1);
    compute(t & 1);
    __syncthreads();
  }

  // park logits (+bias) in LDS f32 [64][LG_STRIDE]
  float* lg = (float*)smem;
#pragma unroll
  for (int mi = 0; mi < 2; ++mi) {
#pragma unroll
    for (int ni = 0; ni < 8; ++ni) {
      const int col = wc * 128 + ni * 16 + r15;
      const float bv = bias[col];
#pragma unroll
      for (int r = 0; r < 4; ++r) {
        const int rowL = wr * 32 + mi * 16 + q * 4 + r;
        lg[rowL * LG_STRIDE + col] = acc[mi][ni][r] + bv;
      }
    }
  }
  __syncthreads();

  // windowed softmax: thread (rowL = tid>>2, p = tid&3) covers k = p*32..p*32+31
  const int rowL = tid >> 2, p = tid & 3;
  const int grow = m0 + rowL;
  const int i = grow & 127;
  float* lrow = lg + rowL * LG_STRIDE + (128 - i) + p * 32;
  float mx = -1e30f;
#pragma unroll
  for (int j = 0; j < 32; ++j) mx = fmaxf(mx, lrow[j]);
  mx = fmaxf(mx, __shfl_xor(mx, 1));
  mx = fmaxf(mx, __shfl_xor(mx, 2));
  float s = 0.f;
#pragma unroll
  for (int j = 0; j < 32; ++j) {
    const float e = __expf(lrow[j] - mx);
    lrow[j] = e;           // own slot; no cross-thread hazard
    s += e;
  }
  s += __shfl_xor(s, 1);
  s += __shfl_xor(s, 2);
  const float scale = p0buf[1] / s;  // (1-p0)/sum
  unsigned int* orow = (unsigned int*)(jwout + (size_t)grow * 128 + p * 32);
#pragma unroll
  for (int j = 0; j < 16; ++j)
    orow[j] = cvt_pk_bf16(lrow[2 * j] * scale, lrow[2 * j + 1] * scale);
}

// ---------- fused HMM forward: in-LDS emission transpose + MFMA recursion ----
#define SE_STRIDE 264  // floats; 1056B row pitch (16B aligned), breaks pow2 banks
__global__ __launch_bounds__(256, 1) void forward_fused(
    const unsigned short* __restrict__ jwb,   // [B][128][128] bf16
    const float* __restrict__ emission,       // [B][256][64]
    const float* __restrict__ p0buf, const int* __restrict__ slen_p,
    const int* __restrict__ tlen_p, float* __restrict__ out) {
  __shared__ __align__(16) float se[64 * SE_STRIDE];
  __shared__ __align__(16) unsigned short gl16[128];
  const int b = blockIdx.x;
  const int tid = threadIdx.x;
  const float* eb = emission + (size_t)b * 16384;

  bf16x8 bfr[4][8];
  const int l = tid & 63;
  const int m = l & 15;
  const int q = l >> 4;

  if (tid >= 64) {
    // transpose emission[b] ([256][64] -> se[t][half*128+m*8+nt])
#pragma unroll
    for (int it = 0; it < 6; ++it) {
      const int tau = (tid - 64) + 192 * it;
      if (tau < 1024) {
        const int t0 = (tau & 15) * 4;
        const int mm = (tau >> 4) & 15;
        const int nt0 = ((tau >> 8) & 1) * 4;
        const int half = (tau >> 9) & 1;
        const int kbase = half * 128 + nt0 * 16 + mm;
        const float4 v0 = *reinterpret_cast<const float4*>(&eb[(size_t)(kbase) * 64 + t0]);
        const float4 v1 = *reinterpret_cast<const float4*>(&eb[(size_t)(kbase + 16) * 64 + t0]);
        const float4 v2 = *reinterpret_cast<const float4*>(&eb[(size_t)(kbase + 32) * 64 + t0]);
        const float4 v3 = *reinterpret_cast<const float4*>(&eb[(size_t)(kbase + 48) * 64 + t0]);
        const int jinv0 = half * 128 + mm * 8 + nt0;
        float* d = &se[(size_t)t0 * SE_STRIDE + jinv0];
        *reinterpret_cast<float4*>(d) = (float4){v0.x, v1.x, v2.x, v3.x};
        *reinterpret_cast<float4*>(d + SE_STRIDE) = (float4){v0.y, v1.y, v2.y, v3.y};
        *reinterpret_cast<float4*>(d + 2 * SE_STRIDE) = (float4){v0.z, v1.z, v2.z, v3.z};
        *reinterpret_cast<float4*>(d + 3 * SE_STRIDE) = (float4){v0.w, v1.w, v2.w, v3.w};
      }
    }
  } else {
    // wave 0: build jw B-frags: bfr[kt][nt][j] = jw[kt*32+q*8+j][nt*16+m]
    const unsigned short* jwt = jwb + (size_t)b * 16384;
#pragma unroll
    for (int kt = 0; kt < 4; ++kt) {
      const int r0 = kt * 32 + q * 8;
#pragma unroll
      for (int nt = 0; nt < 8; ++nt) {
        const int c = nt * 16 + m;
        bf16x8 v;
#pragma unroll
        for (int j = 0; j < 8; ++j) v[j] = (short)jwt[(size_t)(r0 + j) * 128 + c];
        bfr[kt][nt] = v;
      }
    }
  }
  __syncthreads();
  if (tid >= 64) return;

  const float p0 = p0buf[0];
  const int S = slen_p[b];
  const int T = tlen_p[b];

  float gown[8];
  {
    const float4 i0a = *reinterpret_cast<const float4*>(&se[m * 8]);
    const float4 i0b = *reinterpret_cast<const float4*>(&se[m * 8 + 4]);
    const float4 i1a = *reinterpret_cast<const float4*>(&se[128 + m * 8]);
    const float4 i1b = *reinterpret_cast<const float4*>(&se[128 + m * 8 + 4]);
    gown[0] = i0a.x + i1a.x; gown[1] = i0a.y + i1a.y;
    gown[2] = i0a.z + i1a.z; gown[3] = i0a.w + i1a.w;
    gown[4] = i0b.x + i1b.x; gown[5] = i0b.y + i1b.y;
    gown[6] = i0b.z + i1b.z; gown[7] = i0b.w + i1b.w;
  }
  gl16[(2 * q) * 16 + m]     = f2bf(gown[2 * q]);
  gl16[(2 * q + 1) * 16 + m] = f2bf(gown[2 * q + 1]);

  for (int t = 1; t < S; ++t) {
    const float* st = &se[(size_t)t * SE_STRIDE];
    const float4 pe0a = *reinterpret_cast<const float4*>(&st[m * 8]);
    const float4 pe0b = *reinterpret_cast<const float4*>(&st[m * 8 + 4]);
    const float4 pe1a = *reinterpret_cast<const float4*>(&st[128 + m * 8]);
    const float4 pe1b = *reinterpret_cast<const float4*>(&st[128 + m * 8 + 4]);
    const float e0[8] = {pe0a.x, pe0a.y, pe0a.z, pe0a.w, pe0b.x, pe0b.y, pe0b.z, pe0b.w};
    const float e1[8] = {pe1a.x, pe1a.y, pe1a.z, pe1a.w, pe1b.x, pe1b.y, pe1b.z, pe1b.w};
    float h[8];
#pragma unroll
    for (int nt = 0; nt < 8; ++nt) h[nt] = gown[nt] * (p0 * e1[nt]);
    bf16x8 af[4];
#pragma unroll
    for (int kt = 0; kt < 4; ++kt)
      af[kt] = *reinterpret_cast<const bf16x8*>(&gl16[kt * 32 + q * 8]);
    f32x4 acc[8];
#pragma unroll
    for (int nt = 0; nt < 8; ++nt) {
      f32x4 a = __builtin_amdgcn_mfma_f32_16x16x32_bf16(
          af[0], bfr[0][nt], (f32x4){0.f, 0.f, 0.f, 0.f}, 0, 0, 0);
      a = __builtin_amdgcn_mfma_f32_16x16x32_bf16(af[1], bfr[1][nt], a, 0, 0, 0);
      a = __builtin_amdgcn_mfma_f32_16x16x32_bf16(af[2], bfr[2][nt], a, 0, 0, 0);
      acc[nt] = __builtin_amdgcn_mfma_f32_16x16x32_bf16(af[3], bfr[3][nt], a, 0, 0, 0);
    }
#pragma unroll
    for (int nt = 0; nt < 8; ++nt) gown[nt] = fmaf(acc[nt][0], e0[nt], h[nt]);
    gl16[(2 * q) * 16 + m]     = f2bf(gown[2 * q]);
    gl16[(2 * q + 1) * 16 + m] = f2bf(gown[2 * q + 1]);
  }

  float val = 0.f;
#pragma unroll
  for (int nt = 0; nt < 8; ++nt)
    if (nt * 16 + m < T) val += gown[nt];
#pragma unroll
  for (int off = 1; off < 16; off <<= 1) val += __shfl_xor(val, off);
  if (l == 0) out[b] = logf(val + 1e-29f);
}

// ---------- launch ----------
extern "C" void kernel_launch(void* const* d_in, const int* in_sizes, int n_in,
                              void* d_out, int out_size, void* d_ws, size_t ws_size,
                              hipStream_t stream) {
  const float* y_hidden = (const float*)d_in[0];   // [256,128,512]
  const float* y_null   = (const float*)d_in[1];   // [1,1,512]
  const float* W_trans  = (const float*)d_in[2];   // [512,512]
  const float* b_trans  = (const float*)d_in[3];   // [512]
  const float* W_jump   = (const float*)d_in[4];   // [512,257]
  const float* b_jump   = (const float*)d_in[5];   // [257]
  const float* W_p0     = (const float*)d_in[6];   // [512,1]
  const float* b_p0     = (const float*)d_in[7];   // [1]
  const float* emission = (const float*)d_in[8];   // [256,256,64]
  const int* slen = (const int*)d_in[9];
  const int* tlen = (const int*)d_in[10];
  float* out = (float*)d_out;

  char* ws = (char*)d_ws;
  unsigned short* ts16  = (unsigned short*)ws;               // 33,554,432 B
  unsigned short* wt16t = (unsigned short*)(ws + 50331648);  // 524,288 B
  unsigned short* wj16t = (unsigned short*)(ws + 50855936);  // 262,144 B
  float* p0buf          = (float*)(ws + 51118080);           // 256 B
  unsigned short* jwb16 = (unsigned short*)(ws + 51118336);  // 8,388,608 B

  cvt_weights_p0<<<dim3(1537), dim3(256), 0, stream>>>(
      W_trans, W_jump, y_null, b_trans, W_p0, b_p0, wt16t, wj16t, p0buf);

  // GEMM1: ts = tanh(y_f32 @ W_trans + b) -> bf16 (128x256 tile, B-first issue)
  gemm_af32<<<dim3(256, 2), dim3(256), 0, stream>>>(y_hidden, wt16t, b_trans, ts16,
                                                    32768, 512, 512);
  // GEMM2 + windowed softmax fused -> jw bf16 (logits never touch HBM)
  gemm2_sm<<<dim3(512), dim3(256), 0, stream>>>(ts16, wj16t, b_jump, p0buf, jwb16);
  // fused emission-transpose + HMM forward + masked log-sum
  forward_fused<<<dim3(256), dim3(256), 0, stream>>>(jwb16, emission, p0buf,
                                                     slen, tlen, out);
}